// Round 8
// baseline (209.709 us; speedup 1.0000x reference)
//
#include <hip/hip_runtime.h>

// 2-layer GCN, CSR-gather formulation, v8.
//   Â = D^{-1/2}(A+I)D^{-1/2},  out = Â(relu(Â z W1 + b1))W2 + b2
// layer1: t1 = Â z (64-wide), h = relu(t1@W1+b1); layer2: hh = h@W2, out = Â hh + b2.
// v6: CSR build via two-level LDS counting sort by dst — zero global atomics.
// v7: gather operands bf16. v8: (a) operands pre-scaled by dinv[src] (zs=dinv*z;
// matmul2 scales rows) -> CSR weight is raw ew, wscale pass deleted; (b) operand
// split into two 3.2MB feature half-planes, aggregation runs as two sequential
// half-passes so each pass's gather set fits a single XCD's 4MB L2.

#define NPB 128   // nodes per fine bucket (dst & 127 is the in-bucket id)
#define CH  4096  // edges per chunk block in hist/scatter passes

__device__ __forceinline__ float4 ld4(const float* p) {
    return *reinterpret_cast<const float4*>(p);
}

// round-to-nearest-even f32 -> bf16 (as ushort in low bits)
__device__ __forceinline__ unsigned bfr(float f) {
    unsigned u = __float_as_uint(f);
    return (u + 0x7FFFu + ((u >> 16) & 1u)) >> 16;
}
// unpack 4 bf16 (uint2) -> 4 f32
__device__ __forceinline__ void bf4(uint2 v, float& f0, float& f1, float& f2, float& f3) {
    f0 = __uint_as_float(v.x << 16);
    f1 = __uint_as_float(v.x & 0xFFFF0000u);
    f2 = __uint_as_float(v.y << 16);
    f3 = __uint_as_float(v.y & 0xFFFF0000u);
}

// ---- K1: coarse histogram per chunk (LDS), bucket-major out: hist[b*G1+g] ----
__global__ __launch_bounds__(256) void hist_kernel(const int* __restrict__ dst,
                                                   int* __restrict__ hist,
                                                   int E, int G1, int NBKT) {
    __shared__ int lh[512];
    for (int i = threadIdx.x; i < NBKT; i += 256) lh[i] = 0;
    __syncthreads();
    int g = blockIdx.x;
    int beg = g * CH, end = min(beg + CH, E);
    for (int j = beg + (int)threadIdx.x; j < end; j += 256)
        atomicAdd(&lh[dst[j] / NPB], 1);
    __syncthreads();
    for (int i = threadIdx.x; i < NBKT; i += 256) hist[(size_t)i * G1 + g] = lh[i];
}

// ---- K2a: per-bucket exclusive scan across chunks (in place); btot[b] = total ----
__global__ __launch_bounds__(64) void bscan_kernel(int* __restrict__ hist,
                                                   int* __restrict__ btot, int G1) {
    int b = blockIdx.x;
    int* row = hist + (size_t)b * G1;
    int lane = threadIdx.x;
    int carry = 0;
    for (int g0 = 0; g0 < G1; g0 += 64) {
        int g = g0 + lane;
        int v = (g < G1) ? row[g] : 0;
        int incl = v;
#pragma unroll
        for (int off = 1; off < 64; off <<= 1) {
            int u = __shfl_up(incl, off, 64);
            if (lane >= off) incl += u;
        }
        if (g < G1) row[g] = carry + incl - v;
        carry += __shfl(incl, 63, 64);
    }
    if (lane == 0) btot[b] = carry;
}

// ---- K2b: exclusive scan of bucket totals -> bucket bases (NBKT <= 512) ----
__global__ __launch_bounds__(512) void tscan_kernel(const int* __restrict__ btot,
                                                    int* __restrict__ bbase, int NBKT) {
    __shared__ int ws[8];
    int t = threadIdx.x;
    int v = (t < NBKT) ? btot[t] : 0;
    int lane = t & 63, wid = t >> 6;
    int incl = v;
#pragma unroll
    for (int off = 1; off < 64; off <<= 1) {
        int u = __shfl_up(incl, off, 64);
        if (lane >= off) incl += u;
    }
    if (lane == 63) ws[wid] = incl;
    __syncthreads();
    int woff = 0;
#pragma unroll
    for (int w = 0; w < 8; ++w) if (w < wid) woff += ws[w];
    if (t < NBKT) bbase[t] = woff + incl - v;
}

// ---- K3: scatter edges into bucket-grouped tmp via LDS cursors ----
__global__ __launch_bounds__(256) void scatter_kernel(const int* __restrict__ src,
                                                      const int* __restrict__ dst,
                                                      const float* __restrict__ ew,
                                                      const int* __restrict__ hist,
                                                      const int* __restrict__ bbase,
                                                      int2* __restrict__ tmp,
                                                      int E, int G1, int NBKT) {
    __shared__ int cursor[512];
    int g = blockIdx.x;
    for (int i = threadIdx.x; i < NBKT; i += 256)
        cursor[i] = bbase[i] + hist[(size_t)i * G1 + g];
    __syncthreads();
    int beg = g * CH, end = min(beg + CH, E);
    for (int j = beg + (int)threadIdx.x; j < end; j += 256) {
        int d = dst[j];
        int b = d / NPB;
        int pos = atomicAdd(&cursor[b], 1);
        tmp[pos] = make_int2(((d & (NPB - 1)) << 24) | src[j], __float_as_int(ew[j]));
    }
}

// ---- K4: per-bucket finalize: exact rowptr, dinv, final CSR {src, ew} ----
__global__ __launch_bounds__(256) void finalize_kernel(const int2* __restrict__ tmp,
                                                       const int* __restrict__ bbase,
                                                       const int* __restrict__ btot,
                                                       int* __restrict__ rowptr,
                                                       float* __restrict__ dinv,
                                                       int2* __restrict__ csr,
                                                       int n, int E) {
    __shared__ unsigned int hist[NPB];
    __shared__ int wsum_[2];
    int b = blockIdx.x;
    int base = bbase[b];
    int cnt  = btot[b];
    int tid  = threadIdx.x;
    if (tid < NPB) hist[tid] = 0;
    __syncthreads();
    for (int j = tid; j < cnt; j += 256) {
        int2 t = tmp[base + j];
        unsigned dlow = ((unsigned)t.x) >> 24;
        unsigned wfix = (unsigned)(__int_as_float(t.y) * 16384.0f);
        atomicAdd(&hist[dlow], (1u << 24) | wfix);
    }
    __syncthreads();
    int c = 0, incl = 0;
    unsigned pk = 0;
    if (tid < NPB) {
        pk = hist[tid];
        c = (int)(pk >> 24);
        incl = c;
#pragma unroll
        for (int off = 1; off < 64; off <<= 1) {
            int u = __shfl_up(incl, off, 64);
            if ((tid & 63) >= off) incl += u;
        }
        if ((tid & 63) == 63) wsum_[tid >> 6] = incl;
    }
    __syncthreads();
    if (tid < NPB) {
        int woff = (tid >= 64) ? wsum_[0] : 0;
        int excl = woff + incl - c;
        int node = b * NPB + tid;
        if (node < n) {
            rowptr[node] = base + excl;
            float wdeg = (float)(pk & 0xFFFFFFu) * (1.0f / 16384.0f);
            dinv[node] = rsqrtf(wdeg + 1.0f);
        }
        hist[tid] = (unsigned)excl;
    }
    if (b == 0 && tid == 0) rowptr[n] = E;
    __syncthreads();
    for (int j = tid; j < cnt; j += 256) {
        int2 t = tmp[base + j];
        unsigned dlow = ((unsigned)t.x) >> 24;
        int srcv = t.x & 0xFFFFFF;
        int lr = (int)atomicAdd(&hist[dlow], 1u);
        csr[base + lr] = make_int2(srcv, t.y);
    }
}

// ---- K5: zs planes = bf16(dinv[r] * z[r]); plane layout [half][n][8 uint2] ----
__global__ __launch_bounds__(256) void convs_kernel(const float* __restrict__ z,
                                                    const float* __restrict__ dinv,
                                                    uint2* __restrict__ planes, int n) {
    int t = blockIdx.x * 256 + threadIdx.x;
    if (t >= n * 16) return;
    int r = t >> 4, k = t & 15;
    float dv = dinv[r];
    float4 f = ld4(z + (size_t)r * 64 + k * 4);
    uint2 pv = make_uint2(bfr(dv * f.x) | (bfr(dv * f.y) << 16),
                          bfr(dv * f.z) | (bfr(dv * f.w) << 16));
    int half = k >> 3, fq = k & 7;
    planes[(size_t)half * n * 8 + (size_t)r * 8 + fq] = pv;
}

// ---- gather-aggregate half-pass: one wave per dst row, 32 features ----
// Lane l: eg = l>>3 (8 edge subgroups), fq = l&7 (feature uint2 = 4 bf16).
// Hp = pre-scaled bf16 half-plane (zs or hs). out col range [colOff, colOff+32).
// out[row] = (BIAS? b : 0) + dv * ( sum_j ew_j * Hp[src_j] + Hp[row] )
template<bool BIAS>
__global__ __launch_bounds__(256) void gaggh_kernel(const int* __restrict__ rowptr,
                                                    const int2* __restrict__ csr,
                                                    const float* __restrict__ dinv,
                                                    const uint2* __restrict__ Hp,
                                                    const float* __restrict__ b,
                                                    float* __restrict__ out,
                                                    int n, int colOff) {
    int row  = (blockIdx.x * 256 + threadIdx.x) >> 6;
    int lane = threadIdx.x & 63;
    if (row >= n) return;
    int eg = lane >> 3, fq = lane & 7;
    int beg = rowptr[row], end = rowptr[row + 1];
    float dv = dinv[row];

    float ax = 0.f, ay = 0.f, az = 0.f, aw = 0.f;
    float f0, f1, f2, f3;
    int j = beg;
    for (; j + 16 <= end; j += 16) {
        int2 m0 = csr[j + eg];
        int2 m1 = csr[j + eg + 8];
        uint2 v0 = Hp[(size_t)m0.x * 8 + fq];
        uint2 v1 = Hp[(size_t)m1.x * 8 + fq];
        float w0 = __int_as_float(m0.y), w1 = __int_as_float(m1.y);
        bf4(v0, f0, f1, f2, f3);
        ax += w0 * f0; ay += w0 * f1; az += w0 * f2; aw += w0 * f3;
        bf4(v1, f0, f1, f2, f3);
        ax += w1 * f0; ay += w1 * f1; az += w1 * f2; aw += w1 * f3;
    }
    if (j + 8 <= end) {
        int2 m0 = csr[j + eg];
        float w0 = __int_as_float(m0.y);
        uint2 v0 = Hp[(size_t)m0.x * 8 + fq];
        bf4(v0, f0, f1, f2, f3);
        ax += w0 * f0; ay += w0 * f1; az += w0 * f2; aw += w0 * f3;
        j += 8;
    }
    if (j < end) {
        int idx = j + eg;
        if (idx < end) {
            int2 m0 = csr[idx];
            float w0 = __int_as_float(m0.y);
            uint2 v0 = Hp[(size_t)m0.x * 8 + fq];
            bf4(v0, f0, f1, f2, f3);
            ax += w0 * f0; ay += w0 * f1; az += w0 * f2; aw += w0 * f3;
        }
    }
    // combine the 8 edge subgroups (lane bits 3,4,5)
    ax += __shfl_xor(ax,  8, 64); ay += __shfl_xor(ay,  8, 64);
    az += __shfl_xor(az,  8, 64); aw += __shfl_xor(aw,  8, 64);
    ax += __shfl_xor(ax, 16, 64); ay += __shfl_xor(ay, 16, 64);
    az += __shfl_xor(az, 16, 64); aw += __shfl_xor(aw, 16, 64);
    ax += __shfl_xor(ax, 32, 64); ay += __shfl_xor(ay, 32, 64);
    az += __shfl_xor(az, 32, 64); aw += __shfl_xor(aw, 32, 64);

    if (eg == 0) {
        uint2 sv = Hp[(size_t)row * 8 + fq];   // self term (already dinv-scaled)
        float s0, s1, s2, s3;
        bf4(sv, s0, s1, s2, s3);
        float4 o;
        o.x = dv * (ax + s0);
        o.y = dv * (ay + s1);
        o.z = dv * (az + s2);
        o.w = dv * (aw + s3);
        if (BIAS) {
            float4 bb = ld4(b + fq * 4);
            o.x += bb.x; o.y += bb.y; o.z += bb.z; o.w += bb.w;
        }
        *reinterpret_cast<float4*>(out + (size_t)row * 64 + colOff + fq * 4) = o;
    }
}

// ---- dense matmul: Y = (X @ W) [+b] [relu]; OUTB: Y = bf16(dinv[r]*row) planes ----
template<int FIN, int FOUT, bool RELU, bool BIAS, bool OUTB>
__global__ __launch_bounds__(256) void matmulE_kernel(const float* __restrict__ X,
                                                      const float* __restrict__ W,
                                                      const float* __restrict__ b,
                                                      const float* __restrict__ dinv,
                                                      void* __restrict__ Y, int n) {
    constexpr int QPR = FOUT / 4;
    constexpr int RPB = 256 / QPR;
    __shared__ float Ws[FIN * FOUT];
    for (int i = threadIdx.x; i < FIN * FOUT / 4; i += 256)
        reinterpret_cast<float4*>(Ws)[i] = reinterpret_cast<const float4*>(W)[i];
    __syncthreads();

    int r = blockIdx.x * RPB + threadIdx.x / QPR;
    int q = threadIdx.x % QPR;
    if (r >= n) return;
    const float* xr = X + (size_t)r * FIN;

    float ax = 0.f, ay = 0.f, az = 0.f, aw = 0.f;
#pragma unroll
    for (int k = 0; k < FIN; k += 4) {
        float4 a = ld4(xr + k);
        float4 w0 = ld4(&Ws[(k + 0) * FOUT + q * 4]);
        float4 w1 = ld4(&Ws[(k + 1) * FOUT + q * 4]);
        float4 w2 = ld4(&Ws[(k + 2) * FOUT + q * 4]);
        float4 w3 = ld4(&Ws[(k + 3) * FOUT + q * 4]);
        ax += a.x * w0.x + a.y * w1.x + a.z * w2.x + a.w * w3.x;
        ay += a.x * w0.y + a.y * w1.y + a.z * w2.y + a.w * w3.y;
        az += a.x * w0.z + a.y * w1.z + a.z * w2.z + a.w * w3.z;
        aw += a.x * w0.w + a.y * w1.w + a.z * w2.w + a.w * w3.w;
    }
    float4 o = make_float4(ax, ay, az, aw);
    if (BIAS) {
        float4 bb = ld4(b + q * 4);
        o.x += bb.x; o.y += bb.y; o.z += bb.z; o.w += bb.w;
    }
    if (RELU) {
        o.x = fmaxf(o.x, 0.f); o.y = fmaxf(o.y, 0.f);
        o.z = fmaxf(o.z, 0.f); o.w = fmaxf(o.w, 0.f);
    }
    if (OUTB) {
        float dvr = dinv[r];
        o.x *= dvr; o.y *= dvr; o.z *= dvr; o.w *= dvr;
        uint2 pv = make_uint2(bfr(o.x) | (bfr(o.y) << 16),
                              bfr(o.z) | (bfr(o.w) << 16));
        int half = q >> 3, fq = q & 7;
        reinterpret_cast<uint2*>(Y)[(size_t)half * n * 8 + (size_t)r * 8 + fq] = pv;
    } else {
        reinterpret_cast<float4*>(Y)[(size_t)r * QPR + q] = o;
    }
}

extern "C" void kernel_launch(void* const* d_in, const int* in_sizes, int n_in,
                              void* d_out, int out_size, void* d_ws, size_t ws_size,
                              hipStream_t stream) {
    const float* z  = (const float*)d_in[0];
    const int*   ei = (const int*)d_in[1];
    const float* ea = (const float*)d_in[2];
    const float* W1 = (const float*)d_in[3];
    const float* b1 = (const float*)d_in[4];
    const float* W2 = (const float*)d_in[5];
    const float* b2 = (const float*)d_in[6];
    float* out = (float*)d_out;

    const int n = in_sizes[0] / 64;   // LAT = 64
    const int E = in_sizes[2];
    const int* src = ei;
    const int* dst = ei + E;
    const int NBKT = (n + NPB - 1) / NPB;   // 391 for n=50000 (<=512 required)
    const int G1   = (E + CH - 1) / CH;     // chunk blocks

    float* ws = (float*)d_ws;
    size_t p = 0;
    auto alloc = [&](size_t elems) { size_t o = p; p += (elems + 63) & ~63ull; return o; };
    float* dinv   = ws + alloc(n);
    int*   rowptr = (int*)(ws + alloc((size_t)n + 1));
    int*   btot   = (int*)(ws + alloc(NBKT));
    int*   bbase  = (int*)(ws + alloc(NBKT));
    int2*  csr    = (int2*)(ws + alloc((size_t)E * 2));
    float* t1     = ws + alloc((size_t)n * 64);    // Â z (f32), matmul1 input
    uint2* planes = (uint2*)(ws + alloc((size_t)n * 32));  // 2 half-planes: zs, then hs
    // region X: tmp+hist (preprocessing) then h (layers) — tmp dead before h written
    float* X      = ws + alloc((size_t)n * 128);
    int2*  tmp    = (int2*)X;                       // E int2
    int*   hist   = (int*)(X + (size_t)E * 2);      // NBKT*G1 ints
    float* h      = X;
    (void)ws_size;

    // ---- preprocessing: counting sort by dst, zero global atomics ----
    hist_kernel<<<G1, 256, 0, stream>>>(dst, hist, E, G1, NBKT);
    bscan_kernel<<<NBKT, 64, 0, stream>>>(hist, btot, G1);
    tscan_kernel<<<1, 512, 0, stream>>>(btot, bbase, NBKT);
    scatter_kernel<<<G1, 256, 0, stream>>>(src, dst, ea, hist, bbase, tmp, E, G1, NBKT);
    finalize_kernel<<<NBKT, 256, 0, stream>>>(tmp, bbase, btot, rowptr, dinv, csr, n, E);
    convs_kernel<<<(n * 16 + 255) / 256, 256, 0, stream>>>(z, dinv, planes, n);

    const int gblocks = (n + 3) / 4;
    // ---- layer 1: t1 = Â z (two half-passes) ; h = relu(t1 @ W1 + b1) ----
    gaggh_kernel<false><<<gblocks, 256, 0, stream>>>(rowptr, csr, dinv,
                                                     planes, nullptr, t1, n, 0);
    gaggh_kernel<false><<<gblocks, 256, 0, stream>>>(rowptr, csr, dinv,
                                                     planes + (size_t)n * 8, nullptr, t1, n, 32);
    matmulE_kernel<64, 128, true, true, false><<<(n + 7) / 8, 256, 0, stream>>>(
        t1, W1, b1, nullptr, h, n);

    // ---- layer 2: hs = bf16(dinv*(h @ W2)) into planes ; out = Â-gather + b2 ----
    matmulE_kernel<128, 64, false, false, true><<<(n + 15) / 16, 256, 0, stream>>>(
        h, W2, nullptr, dinv, planes, n);
    gaggh_kernel<true><<<gblocks, 256, 0, stream>>>(rowptr, csr, dinv,
                                                    planes, b2, out, n, 0);
    gaggh_kernel<true><<<gblocks, 256, 0, stream>>>(rowptr, csr, dinv,
                                                    planes + (size_t)n * 8, b2 + 32, out, n, 32);
}